// Round 1
// baseline (611.890 us; speedup 1.0000x reference)
//
#include <hip/hip_runtime.h>
#include <math.h>

#define F_IN 256
#define HID  64
#define NC   2

// ---------------------------------------------------------------------------
// Degree / normalization
// ---------------------------------------------------------------------------
__global__ void k_init_cnt(int* __restrict__ cnt, int n) {
    int i = blockIdx.x * blockDim.x + threadIdx.x;
    if (i < n) cnt[i] = 1;   // self-loop contributes 1 to degree
}

__global__ void k_count(const int* __restrict__ dst, int* __restrict__ cnt, int E) {
    int e = blockIdx.x * blockDim.x + threadIdx.x;
    if (e < E) atomicAdd(&cnt[dst[e]], 1);
}

__global__ void k_dinv(const int* __restrict__ cnt, float* __restrict__ dinv, int n) {
    int i = blockIdx.x * blockDim.x + threadIdx.x;
    if (i < n) dinv[i] = rsqrtf((float)cnt[i]);   // deg >= 1 always
}

// ---------------------------------------------------------------------------
// Exclusive scan of (cnt[i]-1)  -> row_ptr  (chunk = 1024 elements per block)
// ---------------------------------------------------------------------------
__global__ __launch_bounds__(256) void k_scan_chunks(const int* __restrict__ cnt,
                                                     int* __restrict__ rp,
                                                     int* __restrict__ partials, int n) {
    __shared__ int sh[256];
    int tid = threadIdx.x;
    int base = blockIdx.x * 1024 + tid * 4;
    int v[4];
    int s = 0;
#pragma unroll
    for (int j = 0; j < 4; j++) {
        int idx = base + j;
        v[j] = (idx < n) ? (cnt[idx] - 1) : 0;   // real (non-self-loop) in-degree
        s += v[j];
    }
    sh[tid] = s;
    __syncthreads();
    int mysum = s;
    for (int off = 1; off < 256; off <<= 1) {
        int t = (tid >= off) ? sh[tid - off] : 0;
        __syncthreads();
        sh[tid] += t;
        __syncthreads();
    }
    int pref = sh[tid] - mysum;   // exclusive prefix across threads in block
#pragma unroll
    for (int j = 0; j < 4; j++) {
        int idx = base + j;
        if (idx < n) rp[idx] = pref;
        pref += v[j];
    }
    if (tid == 255) partials[blockIdx.x] = sh[255];
}

__global__ void k_scan_partials(int* __restrict__ partials, int* __restrict__ rp,
                                int nblk, int n) {
    if (blockIdx.x == 0 && threadIdx.x == 0) {
        int run = 0;
        for (int b = 0; b < nblk; b++) { int t = partials[b]; partials[b] = run; run += t; }
        rp[n] = run;   // == E
    }
}

__global__ void k_add_offsets(int* __restrict__ rp, int* __restrict__ cursor,
                              const int* __restrict__ partials, int n) {
    int i = blockIdx.x * blockDim.x + threadIdx.x;
    if (i < n) {
        int v = rp[i] + partials[i >> 10];
        rp[i] = v;
        cursor[i] = v;
    }
}

// ---------------------------------------------------------------------------
// Scatter edges into CSR (sorted by dst), precompute norm per edge
// ---------------------------------------------------------------------------
__global__ void k_scatter(const int* __restrict__ src, const int* __restrict__ dst,
                          const float* __restrict__ dinv, int* __restrict__ cursor,
                          int* __restrict__ esrc, float* __restrict__ enorm, int E) {
    int e = blockIdx.x * blockDim.x + threadIdx.x;
    if (e < E) {
        int d = dst[e];
        int s = src[e];
        int pos = atomicAdd(&cursor[d], 1);
        esrc[pos] = s;
        enorm[pos] = dinv[s] * dinv[d];
    }
}

// ---------------------------------------------------------------------------
// fp32 GEMM: C[nrows x 64] = A[nrows x K] @ B[K x 64]
// 64-row blocks, 256 threads, 4x4 register tile per thread, A transposed in LDS
// ---------------------------------------------------------------------------
template <int K>
__global__ __launch_bounds__(256) void k_gemm64(const float* __restrict__ A,
                                                const float* __restrict__ B,
                                                float* __restrict__ C, int nrows) {
    __shared__ float As[16][68];   // [k][row], padded: 68*4B = 272B rows (16B aligned)
    __shared__ float Bs[16][64];   // [k][col]

    int tid = threadIdx.x;
    int tx = tid & 15;          // col group -> cols 4*tx .. 4*tx+3
    int ty = tid >> 4;          // row group -> rows 4*ty .. 4*ty+3 (0..15)
    int row0 = blockIdx.x * 64;

    int arow = tid >> 2;        // 0..63
    int ak   = (tid & 3) * 4;   // 0,4,8,12
    int brow = tid >> 4;        // 0..15
    int bcol = (tid & 15) * 4;

    float acc[4][4] = {};

    for (int k0 = 0; k0 < K; k0 += 16) {
        int gr = row0 + arow;
        float4 av = make_float4(0.f, 0.f, 0.f, 0.f);
        if (gr < nrows) av = *(const float4*)(A + (size_t)gr * K + k0 + ak);
        float4 bv = *(const float4*)(B + (size_t)(k0 + brow) * 64 + bcol);
        __syncthreads();   // protect previous iteration's LDS reads
        As[ak + 0][arow] = av.x;
        As[ak + 1][arow] = av.y;
        As[ak + 2][arow] = av.z;
        As[ak + 3][arow] = av.w;
        *(float4*)&Bs[brow][bcol] = bv;
        __syncthreads();
#pragma unroll
        for (int kk = 0; kk < 16; kk++) {
            float4 a = *(const float4*)&As[kk][4 * ty];
            float4 b = *(const float4*)&Bs[kk][4 * tx];
            acc[0][0] += a.x * b.x; acc[0][1] += a.x * b.y; acc[0][2] += a.x * b.z; acc[0][3] += a.x * b.w;
            acc[1][0] += a.y * b.x; acc[1][1] += a.y * b.y; acc[1][2] += a.y * b.z; acc[1][3] += a.y * b.w;
            acc[2][0] += a.z * b.x; acc[2][1] += a.z * b.y; acc[2][2] += a.z * b.z; acc[2][3] += a.z * b.w;
            acc[3][0] += a.w * b.x; acc[3][1] += a.w * b.y; acc[3][2] += a.w * b.z; acc[3][3] += a.w * b.w;
        }
    }
#pragma unroll
    for (int i = 0; i < 4; i++) {
        int row = row0 + 4 * ty + i;
        if (row < nrows) {
            float4 o = make_float4(acc[i][0], acc[i][1], acc[i][2], acc[i][3]);
            *(float4*)(C + (size_t)row * 64 + 4 * tx) = o;
        }
    }
}

// ---------------------------------------------------------------------------
// Aggregation over CSR, 64 features, one wave per node.
// MODE 0: out = relu(agg + bias), written 64-wide (feeds GEMM2)
// MODE 1: v = relu(agg + bias); h3[node] = v @ W3 (wave reduction, fused GEMM3)
// ---------------------------------------------------------------------------
template <int MODE>
__global__ __launch_bounds__(256) void k_agg64(const float* __restrict__ hpre,
                                               const float* __restrict__ dinv,
                                               const int* __restrict__ rp,
                                               const int* __restrict__ esrc,
                                               const float* __restrict__ enorm,
                                               const float* __restrict__ bias,
                                               const float* __restrict__ W3,
                                               float* __restrict__ out, int n) {
    int lane = threadIdx.x & 63;
    int nid = blockIdx.x * 4 + (threadIdx.x >> 6);
    if (nid >= n) return;
    nid = __builtin_amdgcn_readfirstlane(nid);   // wave-uniform -> scalar loads

    float dii = dinv[nid];
    float acc = hpre[(size_t)nid * 64 + lane] * (dii * dii);   // self-loop term
    int e0 = rp[nid];
    int e1 = rp[nid + 1];
    for (int e = e0; e < e1; ++e) {
        int s = esrc[e];
        float w = enorm[e];
        acc += hpre[(size_t)s * 64 + lane] * w;
    }
    acc += bias[lane];
    acc = fmaxf(acc, 0.f);   // relu (both layer 1 and layer 2)

    if (MODE == 0) {
        out[(size_t)nid * 64 + lane] = acc;
    } else {
        // fused GEMM3: h3 = v @ W3, W3 is [64][2] row-major
        float p0 = acc * W3[2 * lane];
        float p1 = acc * W3[2 * lane + 1];
#pragma unroll
        for (int off = 32; off > 0; off >>= 1) {
            p0 += __shfl_xor(p0, off, 64);
            p1 += __shfl_xor(p1, off, 64);
        }
        if (lane == 0) {
            ((float2*)out)[nid] = make_float2(p0, p1);
        }
    }
}

// ---------------------------------------------------------------------------
// Layer-3 aggregation (2-wide) + bias + log_softmax
// ---------------------------------------------------------------------------
__global__ void k_final(const float2* __restrict__ h3, const float* __restrict__ dinv,
                        const int* __restrict__ rp, const int* __restrict__ esrc,
                        const float* __restrict__ enorm, const float* __restrict__ b3,
                        float* __restrict__ out, int n) {
    int i = blockIdx.x * blockDim.x + threadIdx.x;
    if (i >= n) return;
    float dii = dinv[i];
    float2 h = h3[i];
    float a0 = h.x * (dii * dii);
    float a1 = h.y * (dii * dii);
    int e1 = rp[i + 1];
    for (int e = rp[i]; e < e1; ++e) {
        float w = enorm[e];
        float2 hs = h3[esrc[e]];
        a0 += hs.x * w;
        a1 += hs.y * w;
    }
    float l0 = a0 + b3[0];
    float l1 = a1 + b3[1];
    float m = fmaxf(l0, l1);
    float lse = m + logf(expf(l0 - m) + expf(l1 - m));
    out[2 * i + 0] = l0 - lse;
    out[2 * i + 1] = l1 - lse;
}

// ---------------------------------------------------------------------------
// Launch
// ---------------------------------------------------------------------------
extern "C" void kernel_launch(void* const* d_in, const int* in_sizes, int n_in,
                              void* d_out, int out_size, void* d_ws, size_t ws_size,
                              hipStream_t stream) {
    const float* x   = (const float*)d_in[0];
    const int*   ei  = (const int*)d_in[1];
    const float* W1  = (const float*)d_in[2];
    const float* b1  = (const float*)d_in[3];
    const float* W2  = (const float*)d_in[4];
    const float* b2  = (const float*)d_in[5];
    const float* W3  = (const float*)d_in[6];
    const float* b3  = (const float*)d_in[7];
    float* out = (float*)d_out;

    const int N = in_sizes[0] / F_IN;     // 100000
    const int E = in_sizes[1] / 2;        // 1600000
    const int* src = ei;
    const int* dst = ei + E;

    // workspace bump allocator (256B aligned)
    char* p = (char*)d_ws;
    auto alloc = [&](size_t bytes) -> void* {
        void* r = (void*)p;
        p += (bytes + 255) & ~(size_t)255;
        return r;
    };
    int*   cnt      = (int*)alloc((size_t)N * 4);
    float* dinv     = (float*)alloc((size_t)N * 4);
    int*   rp       = (int*)alloc((size_t)(N + 1) * 4);
    int*   cursor   = (int*)alloc((size_t)N * 4);
    int*   partials = (int*)alloc(4096);
    int*   esrc     = (int*)alloc((size_t)E * 4);
    float* enorm    = (float*)alloc((size_t)E * 4);
    float* bufA     = (float*)alloc((size_t)N * HID * 4);
    float* bufB     = (float*)alloc((size_t)N * HID * 4);
    float* h3       = (float*)alloc((size_t)N * NC * 4);

    const int T = 256;
    int gbN = (N + T - 1) / T;
    int gbE = (E + T - 1) / T;
    int nblk = (N + 1023) / 1024;

    // normalization
    k_init_cnt<<<gbN, T, 0, stream>>>(cnt, N);
    k_count<<<gbE, T, 0, stream>>>(dst, cnt, E);
    k_dinv<<<gbN, T, 0, stream>>>(cnt, dinv, N);

    // CSR build
    k_scan_chunks<<<nblk, T, 0, stream>>>(cnt, rp, partials, N);
    k_scan_partials<<<1, 64, 0, stream>>>(partials, rp, nblk, N);
    k_add_offsets<<<gbN, T, 0, stream>>>(rp, cursor, partials, N);
    k_scatter<<<gbE, T, 0, stream>>>(src, dst, dinv, cursor, esrc, enorm, E);

    // layer 1: GEMM then aggregate+relu
    int gemmBlocks = (N + 63) / 64;
    k_gemm64<F_IN><<<gemmBlocks, T, 0, stream>>>(x, W1, bufA, N);
    k_agg64<0><<<(N + 3) / 4, T, 0, stream>>>(bufA, dinv, rp, esrc, enorm, b1, nullptr, bufB, N);

    // layer 2: GEMM then aggregate+relu with fused GEMM3 -> h3
    k_gemm64<HID><<<gemmBlocks, T, 0, stream>>>(bufB, W2, bufA, N);
    k_agg64<1><<<(N + 3) / 4, T, 0, stream>>>(bufA, dinv, rp, esrc, enorm, b2, W3, h3, N);

    // layer 3: aggregate (2-wide) + bias + log_softmax
    k_final<<<gbN, T, 0, stream>>>((const float2*)h3, dinv, rp, esrc, enorm, b3, out, N);
}

// Round 2
// 537.964 us; speedup vs baseline: 1.1374x; 1.1374x over previous
//
#include <hip/hip_runtime.h>
#include <math.h>

#define F_IN 256
#define HID  64
#define NC   2

// ---------------------------------------------------------------------------
// Degree / normalization
// ---------------------------------------------------------------------------
__global__ void k_init_cnt(int* __restrict__ cnt, int n) {
    int i = blockIdx.x * blockDim.x + threadIdx.x;
    if (i < n) cnt[i] = 1;   // self-loop contributes 1 to degree
}

__global__ void k_count(const int* __restrict__ dst, int* __restrict__ cnt, int E) {
    int e = blockIdx.x * blockDim.x + threadIdx.x;
    if (e < E) atomicAdd(&cnt[dst[e]], 1);
}

__global__ void k_dinv(const int* __restrict__ cnt, float* __restrict__ dinv, int n) {
    int i = blockIdx.x * blockDim.x + threadIdx.x;
    if (i < n) dinv[i] = rsqrtf((float)cnt[i]);   // deg >= 1 always
}

// ---------------------------------------------------------------------------
// Exclusive scan of (cnt[i]-1)  -> row_ptr  (chunk = 1024 elements per block)
// ---------------------------------------------------------------------------
__global__ __launch_bounds__(256) void k_scan_chunks(const int* __restrict__ cnt,
                                                     int* __restrict__ rp,
                                                     int* __restrict__ partials, int n) {
    __shared__ int sh[256];
    int tid = threadIdx.x;
    int base = blockIdx.x * 1024 + tid * 4;
    int v[4];
    int s = 0;
#pragma unroll
    for (int j = 0; j < 4; j++) {
        int idx = base + j;
        v[j] = (idx < n) ? (cnt[idx] - 1) : 0;   // real (non-self-loop) in-degree
        s += v[j];
    }
    sh[tid] = s;
    __syncthreads();
    int mysum = s;
    for (int off = 1; off < 256; off <<= 1) {
        int t = (tid >= off) ? sh[tid - off] : 0;
        __syncthreads();
        sh[tid] += t;
        __syncthreads();
    }
    int pref = sh[tid] - mysum;   // exclusive prefix across threads in block
#pragma unroll
    for (int j = 0; j < 4; j++) {
        int idx = base + j;
        if (idx < n) rp[idx] = pref;
        pref += v[j];
    }
    if (tid == 255) partials[blockIdx.x] = sh[255];
}

__global__ void k_scan_partials(int* __restrict__ partials, int* __restrict__ rp,
                                int nblk, int n) {
    if (blockIdx.x == 0 && threadIdx.x == 0) {
        int run = 0;
        for (int b = 0; b < nblk; b++) { int t = partials[b]; partials[b] = run; run += t; }
        rp[n] = run;   // == E
    }
}

__global__ void k_add_offsets(int* __restrict__ rp, int* __restrict__ cursor,
                              const int* __restrict__ partials, int n) {
    int i = blockIdx.x * blockDim.x + threadIdx.x;
    if (i < n) {
        int v = rp[i] + partials[i >> 10];
        rp[i] = v;
        cursor[i] = v;
    }
}

// ---------------------------------------------------------------------------
// Scatter edges into CSR (sorted by dst). Only esrc is written — the edge
// norm is factored out: agg[d] = dinv[d] * sum(h[s]*dinv[s]), with the
// h*dinv scaling fused into the preceding GEMM epilogue.
// ---------------------------------------------------------------------------
__global__ void k_scatter(const int* __restrict__ src, const int* __restrict__ dst,
                          int* __restrict__ cursor, int* __restrict__ esrc, int E) {
    int e = blockIdx.x * blockDim.x + threadIdx.x;
    if (e < E) {
        int d = dst[e];
        int s = src[e];
        int pos = atomicAdd(&cursor[d], 1);
        esrc[pos] = s;
    }
}

// ---------------------------------------------------------------------------
// fp32 GEMM: C[nrows x 64] = (A[nrows x K] @ B[K x 64]) * dinv[row]
// 64-row blocks, 256 threads, 4x4 register tile per thread, A transposed in LDS
// ---------------------------------------------------------------------------
template <int K>
__global__ __launch_bounds__(256) void k_gemm64(const float* __restrict__ A,
                                                const float* __restrict__ B,
                                                const float* __restrict__ dinv,
                                                float* __restrict__ C, int nrows) {
    __shared__ float As[16][68];   // [k][row], padded
    __shared__ float Bs[16][64];   // [k][col]

    int tid = threadIdx.x;
    int tx = tid & 15;          // col group -> cols 4*tx .. 4*tx+3
    int ty = tid >> 4;          // row group -> rows 4*ty .. 4*ty+3 (0..15)
    int row0 = blockIdx.x * 64;

    int arow = tid >> 2;        // 0..63
    int ak   = (tid & 3) * 4;   // 0,4,8,12
    int brow = tid >> 4;        // 0..15
    int bcol = (tid & 15) * 4;

    float acc[4][4] = {};

    for (int k0 = 0; k0 < K; k0 += 16) {
        int gr = row0 + arow;
        float4 av = make_float4(0.f, 0.f, 0.f, 0.f);
        if (gr < nrows) av = *(const float4*)(A + (size_t)gr * K + k0 + ak);
        float4 bv = *(const float4*)(B + (size_t)(k0 + brow) * 64 + bcol);
        __syncthreads();   // protect previous iteration's LDS reads
        As[ak + 0][arow] = av.x;
        As[ak + 1][arow] = av.y;
        As[ak + 2][arow] = av.z;
        As[ak + 3][arow] = av.w;
        *(float4*)&Bs[brow][bcol] = bv;
        __syncthreads();
#pragma unroll
        for (int kk = 0; kk < 16; kk++) {
            float4 a = *(const float4*)&As[kk][4 * ty];
            float4 b = *(const float4*)&Bs[kk][4 * tx];
            acc[0][0] += a.x * b.x; acc[0][1] += a.x * b.y; acc[0][2] += a.x * b.z; acc[0][3] += a.x * b.w;
            acc[1][0] += a.y * b.x; acc[1][1] += a.y * b.y; acc[1][2] += a.y * b.z; acc[1][3] += a.y * b.w;
            acc[2][0] += a.z * b.x; acc[2][1] += a.z * b.y; acc[2][2] += a.z * b.z; acc[2][3] += a.z * b.w;
            acc[3][0] += a.w * b.x; acc[3][1] += a.w * b.y; acc[3][2] += a.w * b.z; acc[3][3] += a.w * b.w;
        }
    }
#pragma unroll
    for (int i = 0; i < 4; i++) {
        int row = row0 + 4 * ty + i;
        if (row < nrows) {
            float di = dinv[row];
            float4 o = make_float4(acc[i][0] * di, acc[i][1] * di, acc[i][2] * di, acc[i][3] * di);
            *(float4*)(C + (size_t)row * 64 + 4 * tx) = o;
        }
    }
}

// ---------------------------------------------------------------------------
// Aggregation over CSR, 64 features, one wave per node. hs = h*dinv rows.
//   a = dinv[nid] * (hs[nid] + sum_{e} hs[esrc[e]]) + bias;  v = relu(a)
// MODE 0: out[nid] = v  (64-wide, feeds GEMM2)
// MODE 1: h3[nid] = (v @ W3) * dinv[nid]   (fused GEMM3, wave reduction)
// ---------------------------------------------------------------------------
template <int MODE>
__global__ __launch_bounds__(256) void k_agg64(const float* __restrict__ hs,
                                               const float* __restrict__ dinv,
                                               const int* __restrict__ rp,
                                               const int* __restrict__ esrc,
                                               const float* __restrict__ bias,
                                               const float* __restrict__ W3,
                                               float* __restrict__ out, int n) {
    int lane = threadIdx.x & 63;
    int nid = blockIdx.x * 4 + (threadIdx.x >> 6);
    if (nid >= n) return;
    nid = __builtin_amdgcn_readfirstlane(nid);   // wave-uniform -> scalar loads

    float dii = dinv[nid];
    int e0 = rp[nid];
    int e1 = rp[nid + 1];

    float acc0 = hs[(size_t)nid * 64 + lane];   // self-loop term (already *dinv)
    float acc1 = 0.f, acc2 = 0.f, acc3 = 0.f;
    int e = e0;
    for (; e + 4 <= e1; e += 4) {
        int s0 = esrc[e + 0];
        int s1 = esrc[e + 1];
        int s2 = esrc[e + 2];
        int s3 = esrc[e + 3];
        acc0 += hs[(size_t)s0 * 64 + lane];
        acc1 += hs[(size_t)s1 * 64 + lane];
        acc2 += hs[(size_t)s2 * 64 + lane];
        acc3 += hs[(size_t)s3 * 64 + lane];
    }
    for (; e < e1; ++e) acc0 += hs[(size_t)esrc[e] * 64 + lane];

    float acc = (acc0 + acc1) + (acc2 + acc3);
    acc = acc * dii + bias[lane];
    acc = fmaxf(acc, 0.f);   // relu

    if (MODE == 0) {
        out[(size_t)nid * 64 + lane] = acc;
    } else {
        // fused GEMM3: h3 = (v @ W3) * dii, W3 is [64][2] row-major
        float2 w3 = ((const float2*)W3)[lane];
        float p0 = acc * w3.x;
        float p1 = acc * w3.y;
#pragma unroll
        for (int off = 32; off > 0; off >>= 1) {
            p0 += __shfl_xor(p0, off, 64);
            p1 += __shfl_xor(p1, off, 64);
        }
        if (lane == 0) {
            ((float2*)out)[nid] = make_float2(p0 * dii, p1 * dii);
        }
    }
}

// ---------------------------------------------------------------------------
// Layer-3 aggregation (2-wide) + bias + log_softmax. h3s rows already *dinv.
// ---------------------------------------------------------------------------
__global__ void k_final(const float2* __restrict__ h3s, const float* __restrict__ dinv,
                        const int* __restrict__ rp, const int* __restrict__ esrc,
                        const float* __restrict__ b3, float* __restrict__ out, int n) {
    int i = blockIdx.x * blockDim.x + threadIdx.x;
    if (i >= n) return;
    float dii = dinv[i];
    float2 h = h3s[i];
    float a0 = h.x;
    float a1 = h.y;
    int e1 = rp[i + 1];
    for (int e = rp[i]; e < e1; ++e) {
        float2 hv = h3s[esrc[e]];
        a0 += hv.x;
        a1 += hv.y;
    }
    float l0 = a0 * dii + b3[0];
    float l1 = a1 * dii + b3[1];
    float m = fmaxf(l0, l1);
    float lse = m + logf(expf(l0 - m) + expf(l1 - m));
    out[2 * i + 0] = l0 - lse;
    out[2 * i + 1] = l1 - lse;
}

// ---------------------------------------------------------------------------
// Launch
// ---------------------------------------------------------------------------
extern "C" void kernel_launch(void* const* d_in, const int* in_sizes, int n_in,
                              void* d_out, int out_size, void* d_ws, size_t ws_size,
                              hipStream_t stream) {
    const float* x   = (const float*)d_in[0];
    const int*   ei  = (const int*)d_in[1];
    const float* W1  = (const float*)d_in[2];
    const float* b1  = (const float*)d_in[3];
    const float* W2  = (const float*)d_in[4];
    const float* b2  = (const float*)d_in[5];
    const float* W3  = (const float*)d_in[6];
    const float* b3  = (const float*)d_in[7];
    float* out = (float*)d_out;

    const int N = in_sizes[0] / F_IN;     // 100000
    const int E = in_sizes[1] / 2;        // 1600000
    const int* src = ei;
    const int* dst = ei + E;

    // workspace bump allocator (256B aligned)
    char* p = (char*)d_ws;
    auto alloc = [&](size_t bytes) -> void* {
        void* r = (void*)p;
        p += (bytes + 255) & ~(size_t)255;
        return r;
    };
    int*   cnt      = (int*)alloc((size_t)N * 4);
    float* dinv     = (float*)alloc((size_t)N * 4);
    int*   rp       = (int*)alloc((size_t)(N + 1) * 4);
    int*   cursor   = (int*)alloc((size_t)N * 4);
    int*   partials = (int*)alloc(4096);
    int*   esrc     = (int*)alloc((size_t)E * 4);
    float* bufA     = (float*)alloc((size_t)N * HID * 4);
    float* bufB     = (float*)alloc((size_t)N * HID * 4);
    float* h3       = (float*)alloc((size_t)N * NC * 4);

    const int T = 256;
    int gbN = (N + T - 1) / T;
    int gbE = (E + T - 1) / T;
    int nblk = (N + 1023) / 1024;

    // normalization
    k_init_cnt<<<gbN, T, 0, stream>>>(cnt, N);
    k_count<<<gbE, T, 0, stream>>>(dst, cnt, E);
    k_dinv<<<gbN, T, 0, stream>>>(cnt, dinv, N);

    // CSR build
    k_scan_chunks<<<nblk, T, 0, stream>>>(cnt, rp, partials, N);
    k_scan_partials<<<1, 64, 0, stream>>>(partials, rp, nblk, N);
    k_add_offsets<<<gbN, T, 0, stream>>>(rp, cursor, partials, N);
    k_scatter<<<gbE, T, 0, stream>>>(src, dst, cursor, esrc, E);

    // layer 1: GEMM (scaled epilogue) then aggregate+relu
    int gemmBlocks = (N + 63) / 64;
    k_gemm64<F_IN><<<gemmBlocks, T, 0, stream>>>(x, W1, dinv, bufA, N);
    k_agg64<0><<<(N + 3) / 4, T, 0, stream>>>(bufA, dinv, rp, esrc, b1, nullptr, bufB, N);

    // layer 2: GEMM (scaled epilogue) then aggregate+relu with fused GEMM3 -> h3
    k_gemm64<HID><<<gemmBlocks, T, 0, stream>>>(bufB, W2, dinv, bufA, N);
    k_agg64<1><<<(N + 3) / 4, T, 0, stream>>>(bufA, dinv, rp, esrc, b2, W3, h3, N);

    // layer 3: aggregate (2-wide) + bias + log_softmax
    k_final<<<gbN, T, 0, stream>>>((const float2*)h3, dinv, rp, esrc, b3, out, N);
}